// Round 1
// baseline (571.456 us; speedup 1.0000x reference)
//
#include <hip/hip_runtime.h>
#include <math.h>

#define GXD 128
#define GYD 128
#define GZD 128
#define VD 28
#define NRAYS 8192
#define NSAMP 128

// One 64-lane wave per ray; each lane owns samples {lane, lane+64}.
// Inclusive cumsum over 128 samples = wave scan (lo) + broadcast total + wave scan (hi).
__global__ __launch_bounds__(256) void plenoxel_kernel(
    const float* __restrict__ grid,
    const float* __restrict__ pos,
    const float* __restrict__ dist,
    const float* __restrict__ ang,
    float* __restrict__ out)
{
    const int wave = threadIdx.x >> 6;
    const int lane = threadIdx.x & 63;
    const int ray  = blockIdx.x * 4 + wave;
    if (ray >= NRAYS) return;

    // --- SH basis (degree 2), computed per-thread (cheap, uniform) ---
    const float theta = ang[0], phi = ang[1];
    float st, ct, sp, cp;
    sincosf(theta, &st, &ct);
    sincosf(phi,   &sp, &cp);
    const float y00 = 0.28209479177387814f;  // 0.5*sqrt(1/pi)
    const float h3  = 0.4886025119029199f;   // 0.5*sqrt(3/pi)
    const float q5  = 0.31539156525252005f;  // 0.25*sqrt(5/pi)
    const float h15 = 1.0925484305920792f;   // 0.5*sqrt(15/pi)
    const float q15 = 0.5462742152960396f;   // 0.25*sqrt(15/pi)
    float basis[9];
    basis[0] = y00;
    basis[1] = h3 * st * sp;
    basis[2] = h3 * ct;
    basis[3] = h3 * st * cp;
    basis[4] = h15 * st * cp * st * sp;
    basis[5] = h15 * st * sp * ct;
    basis[6] = q5 * (3.0f * ct * ct - 1.0f);
    basis[7] = h15 * st * cp * ct;
    basis[8] = q15 * ((st * cp) * (st * cp) - (st * sp) * (st * sp));

    float att_s[2];
    float rgb_s[2][3];

    #pragma unroll
    for (int half = 0; half < 2; ++half) {
        const int s = lane + half * 64;
        const int sidx = ray * NSAMP + s;
        const float px = pos[sidx * 3 + 0];
        const float py = pos[sidx * 3 + 1];
        const float pz = pos[sidx * 3 + 2];
        const int ix = (int)floorf(px);
        const int iy = (int)floorf(py);
        const int iz = (int)floorf(pz);
        const float fx = px - (float)ix;
        const float fy = py - (float)iy;
        const float fz = pz - (float)iz;
        const float wx[2] = {1.0f - fx, fx};
        const float wy[2] = {1.0f - fy, fy};
        const float omz = 1.0f - fz;

        float sig = 0.0f, rr = 0.0f, gg = 0.0f, bb = 0.0f;

        #pragma unroll
        for (int dx = 0; dx < 2; ++dx) {
            #pragma unroll
            for (int dy = 0; dy < 2; ++dy) {
                const float w = wx[dx] * wy[dy];
                // feature vectors for (x,y,z0) and (x,y,z0+1) are contiguous:
                // 28 floats = 112 B each, 16B-aligned -> clean float4 loads.
                const int base = (((ix + dx) * GYD + (iy + dy)) * GZD + iz) * VD;
                const float4* __restrict__ q = (const float4*)(grid + base);
                float f[28];
                #pragma unroll
                for (int i = 0; i < 7; ++i) {
                    const float4 a = q[i];       // z0
                    const float4 c = q[i + 7];   // z0+1
                    f[4 * i + 0] = a.x * omz + c.x * fz;
                    f[4 * i + 1] = a.y * omz + c.y * fz;
                    f[4 * i + 2] = a.z * omz + c.z * fz;
                    f[4 * i + 3] = a.w * omz + c.w * fz;
                }
                sig += w * f[0];
                float r0 = 0.0f, g0 = 0.0f, b0 = 0.0f;
                #pragma unroll
                for (int k = 0; k < 9; ++k) {
                    r0 += basis[k] * f[1 + k];
                    g0 += basis[k] * f[10 + k];
                    b0 += basis[k] * f[19 + k];
                }
                rr += w * r0;
                gg += w * g0;
                bb += w * b0;
            }
        }

        const float tau = sig * dist[sidx];
        att_s[half] = expf(-tau);
        rgb_s[half][0] = rr;
        rgb_s[half][1] = gg;
        rgb_s[half][2] = bb;
    }

    // --- inclusive scan of att over 128 samples ---
    float scan_lo = att_s[0];
    #pragma unroll
    for (int off = 1; off < 64; off <<= 1) {
        const float v = __shfl_up(scan_lo, off, 64);
        if (lane >= off) scan_lo += v;
    }
    const float total_lo = __shfl(scan_lo, 63, 64);

    float scan_hi = att_s[1];
    #pragma unroll
    for (int off = 1; off < 64; off <<= 1) {
        const float v = __shfl_up(scan_hi, off, 64);
        if (lane >= off) scan_hi += v;
    }
    const float T_lo = scan_lo;
    const float T_hi = total_lo + scan_hi;

    const float w_lo = T_lo * (1.0f - att_s[0]);
    const float w_hi = T_hi * (1.0f - att_s[1]);

    float o0 = w_lo * rgb_s[0][0] + w_hi * rgb_s[1][0];
    float o1 = w_lo * rgb_s[0][1] + w_hi * rgb_s[1][1];
    float o2 = w_lo * rgb_s[0][2] + w_hi * rgb_s[1][2];

    // --- wave reduction over 64 lanes ---
    #pragma unroll
    for (int off = 32; off > 0; off >>= 1) {
        o0 += __shfl_xor(o0, off, 64);
        o1 += __shfl_xor(o1, off, 64);
        o2 += __shfl_xor(o2, off, 64);
    }
    if (lane == 0) {
        out[ray * 3 + 0] = o0;
        out[ray * 3 + 1] = o1;
        out[ray * 3 + 2] = o2;
    }
}

extern "C" void kernel_launch(void* const* d_in, const int* in_sizes, int n_in,
                              void* d_out, int out_size, void* d_ws, size_t ws_size,
                              hipStream_t stream) {
    const float* grid = (const float*)d_in[0];  // [128,128,128,28]
    const float* pos  = (const float*)d_in[1];  // [8192,128,3]
    const float* dist = (const float*)d_in[2];  // [8192,128]
    const float* ang  = (const float*)d_in[3];  // [2]
    float* out = (float*)d_out;                 // [8192,3]

    const int block = 256;                       // 4 waves = 4 rays per block
    const int grid_blocks = NRAYS / 4;           // 2048
    plenoxel_kernel<<<grid_blocks, block, 0, stream>>>(grid, pos, dist, ang, out);
}

// Round 2
// 463.983 us; speedup vs baseline: 1.2316x; 1.2316x over previous
//
#include <hip/hip_runtime.h>
#include <math.h>

#define GXD 128
#define GYD 128
#define GZD 128
#define VD 28
#define NRAYS 8192
#define NSAMP 128

// One block (1024 threads) per ray.
// Each sample is handled by 8 lanes: subl = (corner<<1)|zhalf, corner=(dx,dy).
// Everything downstream of the gather (trilinear lerp, sigma, SH dots) is
// linear in the corner features, so each lane computes weighted partials with
// w = wx*wy*wz and an 8-lane shuffle reduction gives the sample's {sig,r,g,b}.
// Wave 0 then performs the inclusive cumsum + weighted RGB accumulation.
__global__ __launch_bounds__(1024) void plenoxel_fused(
    const float* __restrict__ grid,
    const float* __restrict__ pos,
    const float* __restrict__ dist,
    const float* __restrict__ ang,
    float* __restrict__ out)
{
    __shared__ float4 srgb[NSAMP];   // per-sample {sig, r, g, b}

    const int ray  = blockIdx.x;
    const int tid  = threadIdx.x;
    const int s    = tid >> 3;       // sample 0..127
    const int subl = tid & 7;
    const int dx   = (subl >> 2) & 1;
    const int dy   = (subl >> 1) & 1;
    const int zh   = subl & 1;

    // --- SH basis (degree 2) ---
    const float theta = ang[0], phi = ang[1];
    float st, ct, sp, cp;
    sincosf(theta, &st, &ct);
    sincosf(phi,   &sp, &cp);
    const float y00 = 0.28209479177387814f;
    const float h3  = 0.4886025119029199f;
    const float q5  = 0.31539156525252005f;
    const float h15 = 1.0925484305920792f;
    const float q15 = 0.5462742152960396f;
    float basis[9];
    basis[0] = y00;
    basis[1] = h3 * st * sp;
    basis[2] = h3 * ct;
    basis[3] = h3 * st * cp;
    basis[4] = h15 * st * cp * st * sp;
    basis[5] = h15 * st * sp * ct;
    basis[6] = q5 * (3.0f * ct * ct - 1.0f);
    basis[7] = h15 * st * cp * ct;
    basis[8] = q15 * ((st * cp) * (st * cp) - (st * sp) * (st * sp));

    // --- gather: one corner-zhalf per lane ---
    const int sidx = ray * NSAMP + s;
    const float px = pos[sidx * 3 + 0];
    const float py = pos[sidx * 3 + 1];
    const float pz = pos[sidx * 3 + 2];
    const int ix = (int)floorf(px);
    const int iy = (int)floorf(py);
    const int iz = (int)floorf(pz);
    const float fx = px - (float)ix;
    const float fy = py - (float)iy;
    const float fz = pz - (float)iz;

    const float w = (dx ? fx : 1.0f - fx) *
                    (dy ? fy : 1.0f - fy) *
                    (zh ? fz : 1.0f - fz);

    // feature vector base: 28 floats, 16B-aligned (28 = 4*7)
    const int base = (((ix + dx) * GYD + (iy + dy)) * GZD + (iz + zh)) * VD;
    const float4* __restrict__ q = (const float4*)(grid + base);

    float f[28];
    #pragma unroll
    for (int i = 0; i < 7; ++i)
        ((float4*)f)[i] = q[i];

    float psig = w * f[0];
    float pr = 0.0f, pg = 0.0f, pb = 0.0f;
    #pragma unroll
    for (int k = 0; k < 9; ++k) {
        pr += basis[k] * f[1 + k];
        pg += basis[k] * f[10 + k];
        pb += basis[k] * f[19 + k];
    }
    pr *= w; pg *= w; pb *= w;

    // reduce over the 8-lane group (group boundaries are multiples of 8)
    #pragma unroll
    for (int off = 1; off < 8; off <<= 1) {
        psig += __shfl_xor(psig, off, 64);
        pr   += __shfl_xor(pr,   off, 64);
        pg   += __shfl_xor(pg,   off, 64);
        pb   += __shfl_xor(pb,   off, 64);
    }
    if (subl == 0) srgb[s] = make_float4(psig, pr, pg, pb);
    __syncthreads();

    // --- wave 0: inclusive scan over 128 samples + weighted RGB sum ---
    if (tid < 64) {
        const int lane = tid;
        const float4 a0 = srgb[lane];
        const float4 a1 = srgb[lane + 64];
        const float d0 = dist[ray * NSAMP + lane];
        const float d1 = dist[ray * NSAMP + lane + 64];
        const float att0 = expf(-a0.x * d0);
        const float att1 = expf(-a1.x * d1);

        float scan_lo = att0;
        #pragma unroll
        for (int off = 1; off < 64; off <<= 1) {
            const float v = __shfl_up(scan_lo, off, 64);
            if (lane >= off) scan_lo += v;
        }
        const float total_lo = __shfl(scan_lo, 63, 64);

        float scan_hi = att1;
        #pragma unroll
        for (int off = 1; off < 64; off <<= 1) {
            const float v = __shfl_up(scan_hi, off, 64);
            if (lane >= off) scan_hi += v;
        }
        const float T_lo = scan_lo;
        const float T_hi = total_lo + scan_hi;

        const float w_lo = T_lo * (1.0f - att0);
        const float w_hi = T_hi * (1.0f - att1);

        float o0 = w_lo * a0.y + w_hi * a1.y;
        float o1 = w_lo * a0.z + w_hi * a1.z;
        float o2 = w_lo * a0.w + w_hi * a1.w;

        #pragma unroll
        for (int off = 32; off > 0; off >>= 1) {
            o0 += __shfl_xor(o0, off, 64);
            o1 += __shfl_xor(o1, off, 64);
            o2 += __shfl_xor(o2, off, 64);
        }
        if (lane == 0) {
            out[ray * 3 + 0] = o0;
            out[ray * 3 + 1] = o1;
            out[ray * 3 + 2] = o2;
        }
    }
}

extern "C" void kernel_launch(void* const* d_in, const int* in_sizes, int n_in,
                              void* d_out, int out_size, void* d_ws, size_t ws_size,
                              hipStream_t stream) {
    const float* grid = (const float*)d_in[0];  // [128,128,128,28]
    const float* pos  = (const float*)d_in[1];  // [8192,128,3]
    const float* dist = (const float*)d_in[2];  // [8192,128]
    const float* ang  = (const float*)d_in[3];  // [2]
    float* out = (float*)d_out;                 // [8192,3]

    plenoxel_fused<<<NRAYS, 1024, 0, stream>>>(grid, pos, dist, ang, out);
}

// Round 3
// 446.239 us; speedup vs baseline: 1.2806x; 1.0398x over previous
//
#include <hip/hip_runtime.h>
#include <hip/hip_fp16.h>
#include <math.h>

#define GXD 128
#define GYD 128
#define GZD 128
#define VD 28
#define VDP 32          // padded feature count in fp16 scratch copy
#define NRAYS 8192
#define NSAMP 128

// ---------- pass 1: fp32 grid -> fp16 (padded 28->32) in d_ws ----------
// 134 MiB output fits in the 256 MiB Infinity Cache alongside pos/dist.
__global__ __launch_bounds__(256) void convert_grid(
    const float* __restrict__ g, __half* __restrict__ h)
{
    const unsigned t = blockIdx.x * 256u + threadIdx.x;   // one half2 per thread
    const unsigned o = t << 1;                            // output half index
    const unsigned v = o >> 5;                            // voxel
    const unsigned k = o & 31;                            // feature pair base
    __half2 out;
    if (k < VD) {
        const float2 f = *(const float2*)(g + v * VD + k); // 8B-aligned
        out = __floats2half2_rn(f.x, f.y);
    } else {
        out = __floats2half2_rn(0.0f, 0.0f);
    }
    *(__half2*)(h + o) = out;
}

// ---------- pass 2: fused render from fp16 grid ----------
// One block (1024 threads) per ray; 8 lanes per sample (one per corner).
// Each lane loads its corner's 64 B (4x float4) -> 28 fp16 features,
// computes weighted partial {sig,r,g,b}, 8-lane shuffle reduce,
// wave 0 does the inclusive-cumsum + weighted RGB sum.
__global__ __launch_bounds__(1024) void plenoxel_fused16(
    const __half* __restrict__ hg,
    const float* __restrict__ pos,
    const float* __restrict__ dist,
    const float* __restrict__ ang,
    float* __restrict__ out)
{
    __shared__ float4 srgb[NSAMP];

    const int ray  = blockIdx.x;
    const int tid  = threadIdx.x;
    const int s    = tid >> 3;
    const int subl = tid & 7;
    const int dx   = (subl >> 2) & 1;
    const int dy   = (subl >> 1) & 1;
    const int zh   = subl & 1;

    // --- SH basis ---
    const float theta = ang[0], phi = ang[1];
    float st, ct, sp, cp;
    sincosf(theta, &st, &ct);
    sincosf(phi,   &sp, &cp);
    float basis[9];
    basis[0] = 0.28209479177387814f;
    basis[1] = 0.4886025119029199f * st * sp;
    basis[2] = 0.4886025119029199f * ct;
    basis[3] = 0.4886025119029199f * st * cp;
    basis[4] = 1.0925484305920792f * st * cp * st * sp;
    basis[5] = 1.0925484305920792f * st * sp * ct;
    basis[6] = 0.31539156525252005f * (3.0f * ct * ct - 1.0f);
    basis[7] = 1.0925484305920792f * st * cp * ct;
    basis[8] = 0.5462742152960396f * ((st * cp) * (st * cp) - (st * sp) * (st * sp));

    const int sidx = ray * NSAMP + s;
    const float px = pos[sidx * 3 + 0];
    const float py = pos[sidx * 3 + 1];
    const float pz = pos[sidx * 3 + 2];
    const int ix = (int)floorf(px);
    const int iy = (int)floorf(py);
    const int iz = (int)floorf(pz);
    const float fx = px - (float)ix;
    const float fy = py - (float)iy;
    const float fz = pz - (float)iz;

    const float w = (dx ? fx : 1.0f - fx) *
                    (dy ? fy : 1.0f - fy) *
                    (zh ? fz : 1.0f - fz);

    // corner voxel: 32 halfs = 64 B, 64B-aligned
    const int base = (((ix + dx) * GYD + (iy + dy)) * GZD + (iz + zh)) * VDP;
    const float4* __restrict__ q = (const float4*)(hg + base);

    float4 raw[4];
    raw[0] = q[0]; raw[1] = q[1]; raw[2] = q[2]; raw[3] = q[3];
    const __half* f = (const __half*)raw;

    float sig = __half2float(f[0]);
    float r = 0.0f, g = 0.0f, b = 0.0f;
    #pragma unroll
    for (int k = 0; k < 9; ++k) {
        r += basis[k] * __half2float(f[1 + k]);
        g += basis[k] * __half2float(f[10 + k]);
        b += basis[k] * __half2float(f[19 + k]);
    }
    float psig = w * sig;
    float pr = w * r, pg = w * g, pb = w * b;

    #pragma unroll
    for (int off = 1; off < 8; off <<= 1) {
        psig += __shfl_xor(psig, off, 64);
        pr   += __shfl_xor(pr,   off, 64);
        pg   += __shfl_xor(pg,   off, 64);
        pb   += __shfl_xor(pb,   off, 64);
    }
    if (subl == 0) srgb[s] = make_float4(psig, pr, pg, pb);
    __syncthreads();

    if (tid < 64) {
        const int lane = tid;
        const float4 a0 = srgb[lane];
        const float4 a1 = srgb[lane + 64];
        const float d0 = dist[ray * NSAMP + lane];
        const float d1 = dist[ray * NSAMP + lane + 64];
        const float att0 = expf(-a0.x * d0);
        const float att1 = expf(-a1.x * d1);

        float scan_lo = att0;
        #pragma unroll
        for (int off = 1; off < 64; off <<= 1) {
            const float v = __shfl_up(scan_lo, off, 64);
            if (lane >= off) scan_lo += v;
        }
        const float total_lo = __shfl(scan_lo, 63, 64);

        float scan_hi = att1;
        #pragma unroll
        for (int off = 1; off < 64; off <<= 1) {
            const float v = __shfl_up(scan_hi, off, 64);
            if (lane >= off) scan_hi += v;
        }
        const float w_lo = scan_lo * (1.0f - att0);
        const float w_hi = (total_lo + scan_hi) * (1.0f - att1);

        float o0 = w_lo * a0.y + w_hi * a1.y;
        float o1 = w_lo * a0.z + w_hi * a1.z;
        float o2 = w_lo * a0.w + w_hi * a1.w;

        #pragma unroll
        for (int off = 32; off > 0; off >>= 1) {
            o0 += __shfl_xor(o0, off, 64);
            o1 += __shfl_xor(o1, off, 64);
            o2 += __shfl_xor(o2, off, 64);
        }
        if (lane == 0) {
            out[ray * 3 + 0] = o0;
            out[ray * 3 + 1] = o1;
            out[ray * 3 + 2] = o2;
        }
    }
}

// ---------- fallback: proven fp32 kernel (round 2) if ws too small ----------
__global__ __launch_bounds__(1024) void plenoxel_fused32(
    const float* __restrict__ grid,
    const float* __restrict__ pos,
    const float* __restrict__ dist,
    const float* __restrict__ ang,
    float* __restrict__ out)
{
    __shared__ float4 srgb[NSAMP];
    const int ray  = blockIdx.x;
    const int tid  = threadIdx.x;
    const int s    = tid >> 3;
    const int subl = tid & 7;
    const int dx   = (subl >> 2) & 1;
    const int dy   = (subl >> 1) & 1;
    const int zh   = subl & 1;

    const float theta = ang[0], phi = ang[1];
    float st, ct, sp, cp;
    sincosf(theta, &st, &ct);
    sincosf(phi,   &sp, &cp);
    float basis[9];
    basis[0] = 0.28209479177387814f;
    basis[1] = 0.4886025119029199f * st * sp;
    basis[2] = 0.4886025119029199f * ct;
    basis[3] = 0.4886025119029199f * st * cp;
    basis[4] = 1.0925484305920792f * st * cp * st * sp;
    basis[5] = 1.0925484305920792f * st * sp * ct;
    basis[6] = 0.31539156525252005f * (3.0f * ct * ct - 1.0f);
    basis[7] = 1.0925484305920792f * st * cp * ct;
    basis[8] = 0.5462742152960396f * ((st * cp) * (st * cp) - (st * sp) * (st * sp));

    const int sidx = ray * NSAMP + s;
    const float px = pos[sidx * 3 + 0];
    const float py = pos[sidx * 3 + 1];
    const float pz = pos[sidx * 3 + 2];
    const int ix = (int)floorf(px);
    const int iy = (int)floorf(py);
    const int iz = (int)floorf(pz);
    const float fx = px - (float)ix;
    const float fy = py - (float)iy;
    const float fz = pz - (float)iz;

    const float w = (dx ? fx : 1.0f - fx) *
                    (dy ? fy : 1.0f - fy) *
                    (zh ? fz : 1.0f - fz);

    const int base = (((ix + dx) * GYD + (iy + dy)) * GZD + (iz + zh)) * VD;
    const float4* __restrict__ q = (const float4*)(grid + base);
    float f[28];
    #pragma unroll
    for (int i = 0; i < 7; ++i)
        ((float4*)f)[i] = q[i];

    float psig = w * f[0];
    float pr = 0.0f, pg = 0.0f, pb = 0.0f;
    #pragma unroll
    for (int k = 0; k < 9; ++k) {
        pr += basis[k] * f[1 + k];
        pg += basis[k] * f[10 + k];
        pb += basis[k] * f[19 + k];
    }
    pr *= w; pg *= w; pb *= w;

    #pragma unroll
    for (int off = 1; off < 8; off <<= 1) {
        psig += __shfl_xor(psig, off, 64);
        pr   += __shfl_xor(pr,   off, 64);
        pg   += __shfl_xor(pg,   off, 64);
        pb   += __shfl_xor(pb,   off, 64);
    }
    if (subl == 0) srgb[s] = make_float4(psig, pr, pg, pb);
    __syncthreads();

    if (tid < 64) {
        const int lane = tid;
        const float4 a0 = srgb[lane];
        const float4 a1 = srgb[lane + 64];
        const float d0 = dist[ray * NSAMP + lane];
        const float d1 = dist[ray * NSAMP + lane + 64];
        const float att0 = expf(-a0.x * d0);
        const float att1 = expf(-a1.x * d1);

        float scan_lo = att0;
        #pragma unroll
        for (int off = 1; off < 64; off <<= 1) {
            const float v = __shfl_up(scan_lo, off, 64);
            if (lane >= off) scan_lo += v;
        }
        const float total_lo = __shfl(scan_lo, 63, 64);
        float scan_hi = att1;
        #pragma unroll
        for (int off = 1; off < 64; off <<= 1) {
            const float v = __shfl_up(scan_hi, off, 64);
            if (lane >= off) scan_hi += v;
        }
        const float w_lo = scan_lo * (1.0f - att0);
        const float w_hi = (total_lo + scan_hi) * (1.0f - att1);

        float o0 = w_lo * a0.y + w_hi * a1.y;
        float o1 = w_lo * a0.z + w_hi * a1.z;
        float o2 = w_lo * a0.w + w_hi * a1.w;
        #pragma unroll
        for (int off = 32; off > 0; off >>= 1) {
            o0 += __shfl_xor(o0, off, 64);
            o1 += __shfl_xor(o1, off, 64);
            o2 += __shfl_xor(o2, off, 64);
        }
        if (lane == 0) {
            out[ray * 3 + 0] = o0;
            out[ray * 3 + 1] = o1;
            out[ray * 3 + 2] = o2;
        }
    }
}

extern "C" void kernel_launch(void* const* d_in, const int* in_sizes, int n_in,
                              void* d_out, int out_size, void* d_ws, size_t ws_size,
                              hipStream_t stream) {
    const float* grid = (const float*)d_in[0];
    const float* pos  = (const float*)d_in[1];
    const float* dist = (const float*)d_in[2];
    const float* ang  = (const float*)d_in[3];
    float* out = (float*)d_out;

    const size_t need = (size_t)GXD * GYD * GZD * VDP * sizeof(__half); // 128 MiB
    if (ws_size >= need) {
        __half* hg = (__half*)d_ws;
        const unsigned n_half2 = (unsigned)((size_t)GXD * GYD * GZD * VDP / 2);
        convert_grid<<<n_half2 / 256, 256, 0, stream>>>(grid, hg);
        plenoxel_fused16<<<NRAYS, 1024, 0, stream>>>(hg, pos, dist, ang, out);
    } else {
        plenoxel_fused32<<<NRAYS, 1024, 0, stream>>>(grid, pos, dist, ang, out);
    }
}